// Round 1
// baseline (189.897 us; speedup 1.0000x reference)
//
#include <hip/hip_runtime.h>
#include <stdint.h>

#define B 8
#define N 8192
#define D 512
#define C 2
#define K 512
#define DIV_W 0.3f
#define UNC_W 0.3f

constexpr int ROWS_PER_WAVE  = 16;
constexpr int WAVES_PER_BLK  = 4;
constexpr int ROWS_PER_BLOCK = ROWS_PER_WAVE * WAVES_PER_BLK;  // 64
constexpr int BLOCKS_PER_B   = N / ROWS_PER_BLOCK;             // 128

// ---------------------------------------------------------------------------
// Pass 1: per-row inverse norm + accumulate s[b][d] = sum_n x_norm[b][n][d]
// ---------------------------------------------------------------------------
__global__ __launch_bounds__(256) void k_norm_s(const float* __restrict__ x,
                                                float* __restrict__ inv_norm,
                                                float* __restrict__ s) {
    int blk  = blockIdx.x;
    int b    = blk / BLOCKS_PER_B;
    int rb   = (blk % BLOCKS_PER_B) * ROWS_PER_BLOCK;
    int tid  = threadIdx.x;
    int wave = tid >> 6;
    int lane = tid & 63;

    const float4* xb = (const float4*)(x + (size_t)b * N * D);

    float4 accA = {0.f, 0.f, 0.f, 0.f};
    float4 accB = {0.f, 0.f, 0.f, 0.f};

    int row0 = rb + wave * ROWS_PER_WAVE;
    for (int r = 0; r < ROWS_PER_WAVE; ++r) {
        int row = row0 + r;
        const float4* xr = xb + (size_t)row * (D / 4);
        float4 a  = xr[lane];        // floats d = lane*4 .. lane*4+3
        float4 bb = xr[64 + lane];   // floats d = 256 + lane*4 ..

        float ss = a.x*a.x + a.y*a.y + a.z*a.z + a.w*a.w
                 + bb.x*bb.x + bb.y*bb.y + bb.z*bb.z + bb.w*bb.w;
        #pragma unroll
        for (int o = 32; o > 0; o >>= 1) ss += __shfl_xor(ss, o, 64);

        float inv = 1.0f / fmaxf(sqrtf(ss), 1e-12f);
        if (lane == 0) inv_norm[b * N + row] = inv;

        accA.x += a.x * inv;  accA.y += a.y * inv;
        accA.z += a.z * inv;  accA.w += a.w * inv;
        accB.x += bb.x * inv; accB.y += bb.y * inv;
        accB.z += bb.z * inv; accB.w += bb.w * inv;
    }

    __shared__ float sp[WAVES_PER_BLK][D];
    float* dA = &sp[wave][lane * 4];
    dA[0] = accA.x; dA[1] = accA.y; dA[2] = accA.z; dA[3] = accA.w;
    float* dB = &sp[wave][256 + lane * 4];
    dB[0] = accB.x; dB[1] = accB.y; dB[2] = accB.z; dB[3] = accB.w;
    __syncthreads();

    for (int d = tid; d < D; d += 256) {
        float v = sp[0][d] + sp[1][d] + sp[2][d] + sp[3][d];
        atomicAdd(&s[b * D + d], v);
    }
}

// ---------------------------------------------------------------------------
// Pass 2: combined[b][n] = relevance + 0.3*diversity + 0.3*entropy
// ---------------------------------------------------------------------------
__global__ __launch_bounds__(256) void k_combined(const float* __restrict__ x,
                                                  const float* __restrict__ c,
                                                  const float* __restrict__ inv_norm,
                                                  const float* __restrict__ s,
                                                  float* __restrict__ combined) {
    __shared__ float sl[D];
    int blk  = blockIdx.x;
    int b    = blk / BLOCKS_PER_B;
    int rb   = (blk % BLOCKS_PER_B) * ROWS_PER_BLOCK;
    int tid  = threadIdx.x;
    int wave = tid >> 6;
    int lane = tid & 63;

    for (int d = tid; d < D; d += 256) sl[d] = s[b * D + d];
    __syncthreads();

    const float4* sv = (const float4*)sl;
    float4 sA = sv[lane];
    float4 sB = sv[64 + lane];

    const float4* xb = (const float4*)(x + (size_t)b * N * D);
    int row0 = rb + wave * ROWS_PER_WAVE;
    for (int r = 0; r < ROWS_PER_WAVE; ++r) {
        int row = row0 + r;
        const float4* xr = xb + (size_t)row * (D / 4);
        float4 a  = xr[lane];
        float4 bb = xr[64 + lane];

        float dot = a.x*sA.x + a.y*sA.y + a.z*sA.z + a.w*sA.w
                  + bb.x*sB.x + bb.y*sB.y + bb.z*sB.z + bb.w*sB.w;
        #pragma unroll
        for (int o = 32; o > 0; o >>= 1) dot += __shfl_xor(dot, o, 64);

        if (lane == 0) {
            float rs  = dot * inv_norm[b * N + row];
            float div = 1.0f - (rs - 1.0f) / (float)(N - 1);

            const float* cc = c + ((size_t)b * N + row) * C;
            float c0 = cc[0], c1 = cc[1];
            float rel = fmaxf(c0, c1);
            float m  = rel;
            float e0 = expf(c0 - m), e1 = expf(c1 - m);
            float Z  = e0 + e1;
            float p0 = e0 / Z, p1 = e1 / Z;
            float ent = -(p0 * logf(p0 + 1e-8f) + p1 * logf(p1 + 1e-8f));

            combined[b * N + row] = rel + DIV_W * div + UNC_W * ent;
        }
    }
}

// ---------------------------------------------------------------------------
// Pass 3: attention weights = softmax(combined) over N, per batch
// ---------------------------------------------------------------------------
__global__ __launch_bounds__(1024) void k_softmax(const float* __restrict__ combined,
                                                  float* __restrict__ out_w) {
    int b   = blockIdx.x;
    int tid = threadIdx.x;
    int wave = tid >> 6, lane = tid & 63;
    const float* cb = combined + b * N;

    float v[N / 1024];
    float m = -INFINITY;
    #pragma unroll
    for (int i = 0; i < N / 1024; ++i) {
        v[i] = cb[tid + i * 1024];
        m = fmaxf(m, v[i]);
    }
    #pragma unroll
    for (int o = 32; o > 0; o >>= 1) m = fmaxf(m, __shfl_xor(m, o, 64));

    __shared__ float redm[16];
    __shared__ float reds[16];
    if (lane == 0) redm[wave] = m;
    __syncthreads();
    float bm = redm[0];
    #pragma unroll
    for (int i = 1; i < 16; ++i) bm = fmaxf(bm, redm[i]);

    float sum = 0.f;
    #pragma unroll
    for (int i = 0; i < N / 1024; ++i) {
        v[i] = expf(v[i] - bm);
        sum += v[i];
    }
    #pragma unroll
    for (int o = 32; o > 0; o >>= 1) sum += __shfl_xor(sum, o, 64);
    if (lane == 0) reds[wave] = sum;
    __syncthreads();
    float tot = 0.f;
    #pragma unroll
    for (int i = 0; i < 16; ++i) tot += reds[i];

    float invZ = 1.0f / tot;
    #pragma unroll
    for (int i = 0; i < N / 1024; ++i)
        out_w[b * N + tid + i * 1024] = v[i] * invZ;
}

// ---------------------------------------------------------------------------
// Pass 4: exact top-K via full bitonic sort of packed (value, ~idx) keys.
// Key = ord(float)<<32 | (N-1-idx) -> descending sort == jax.lax.top_k order
// (values descending, ties broken by lower index first).
// ---------------------------------------------------------------------------
__global__ __launch_bounds__(1024) void k_topk(const float* __restrict__ combined,
                                               float* __restrict__ out_idx) {
    __shared__ unsigned long long keys[N];  // 64 KiB
    int b   = blockIdx.x;
    int tid = threadIdx.x;
    const float* cb = combined + b * N;

    for (int i = tid; i < N; i += 1024) {
        unsigned u = __float_as_uint(cb[i]);
        u = (u & 0x80000000u) ? ~u : (u | 0x80000000u);  // order-preserving map
        keys[i] = ((unsigned long long)u << 32) | (unsigned)(N - 1 - i);
    }
    __syncthreads();

    for (int k = 2; k <= N; k <<= 1) {
        for (int j = k >> 1; j > 0; j >>= 1) {
            for (int t = tid; t < N; t += 1024) {
                int ixj = t ^ j;
                if (ixj > t) {
                    unsigned long long a = keys[t], bb = keys[ixj];
                    bool desc = ((t & k) == 0);
                    if (desc ? (a < bb) : (a > bb)) { keys[t] = bb; keys[ixj] = a; }
                }
            }
            __syncthreads();
        }
    }

    for (int p = tid; p < K; p += 1024) {
        unsigned idx = (unsigned)(N - 1) - (unsigned)(keys[p] & 0xffffffffu);
        out_idx[b * K + p] = (float)idx;
    }
}

// ---------------------------------------------------------------------------
extern "C" void kernel_launch(void* const* d_in, const int* in_sizes, int n_in,
                              void* d_out, int out_size, void* d_ws, size_t ws_size,
                              hipStream_t stream) {
    const float* x = (const float*)d_in[0];
    const float* c = (const float*)d_in[1];

    float* ws       = (float*)d_ws;
    float* s        = ws;                  // B*D      = 4096 floats
    float* inv_norm = s + B * D;           // B*N      = 65536 floats
    float* combined = inv_norm + B * N;    // B*N      = 65536 floats

    float* out = (float*)d_out;            // [B*K indices][B*N weights]

    hipMemsetAsync(s, 0, B * D * sizeof(float), stream);

    k_norm_s  <<<B * BLOCKS_PER_B, 256, 0, stream>>>(x, inv_norm, s);
    k_combined<<<B * BLOCKS_PER_B, 256, 0, stream>>>(x, c, inv_norm, s, combined);
    k_softmax <<<B, 1024, 0, stream>>>(combined, out + B * K);
    k_topk    <<<B, 1024, 0, stream>>>(combined, out);
}

// Round 2
// 81.583 us; speedup vs baseline: 2.3277x; 2.3277x over previous
//
#include <hip/hip_runtime.h>
#include <stdint.h>

#define B 8
#define N 8192
#define D 512
#define C 2
#define K 512
#define DIV_W 0.3f
#define UNC_W 0.3f

constexpr int ROWS_PER_WAVE  = 16;
constexpr int WAVES_PER_BLK  = 4;
constexpr int ROWS_PER_BLOCK = ROWS_PER_WAVE * WAVES_PER_BLK;  // 64
constexpr int BLOCKS_PER_B   = N / ROWS_PER_BLOCK;             // 128

// Order-preserving float<->u32 map (monotone: f1<f2 <=> ord(f1)<ord(f2))
__device__ __forceinline__ uint32_t ordmap(float f) {
    uint32_t u = __float_as_uint(f);
    return (u & 0x80000000u) ? ~u : (u | 0x80000000u);
}
__device__ __forceinline__ float ordunmap(uint32_t u) {
    return (u >> 31) ? __uint_as_float(u & 0x7FFFFFFFu) : __uint_as_float(~u);
}

// ---------------------------------------------------------------------------
// Pass 1: per-row inverse norm + accumulate s[b][d] = sum_n x_norm[b][n][d]
// ---------------------------------------------------------------------------
__global__ __launch_bounds__(256) void k_norm_s(const float* __restrict__ x,
                                                float* __restrict__ inv_norm,
                                                float* __restrict__ s) {
    int blk  = blockIdx.x;
    int b    = blk / BLOCKS_PER_B;
    int rb   = (blk % BLOCKS_PER_B) * ROWS_PER_BLOCK;
    int tid  = threadIdx.x;
    int wave = tid >> 6;
    int lane = tid & 63;

    const float4* xb = (const float4*)(x + (size_t)b * N * D);

    float4 accA = {0.f, 0.f, 0.f, 0.f};
    float4 accB = {0.f, 0.f, 0.f, 0.f};

    int row0 = rb + wave * ROWS_PER_WAVE;
    for (int r = 0; r < ROWS_PER_WAVE; ++r) {
        int row = row0 + r;
        const float4* xr = xb + (size_t)row * (D / 4);
        float4 a  = xr[lane];
        float4 bb = xr[64 + lane];

        float ss = a.x*a.x + a.y*a.y + a.z*a.z + a.w*a.w
                 + bb.x*bb.x + bb.y*bb.y + bb.z*bb.z + bb.w*bb.w;
        #pragma unroll
        for (int o = 32; o > 0; o >>= 1) ss += __shfl_xor(ss, o, 64);

        float inv = 1.0f / fmaxf(sqrtf(ss), 1e-12f);
        if (lane == 0) inv_norm[b * N + row] = inv;

        accA.x += a.x * inv;  accA.y += a.y * inv;
        accA.z += a.z * inv;  accA.w += a.w * inv;
        accB.x += bb.x * inv; accB.y += bb.y * inv;
        accB.z += bb.z * inv; accB.w += bb.w * inv;
    }

    __shared__ float sp[WAVES_PER_BLK][D];
    float* dA = &sp[wave][lane * 4];
    dA[0] = accA.x; dA[1] = accA.y; dA[2] = accA.z; dA[3] = accA.w;
    float* dB = &sp[wave][256 + lane * 4];
    dB[0] = accB.x; dB[1] = accB.y; dB[2] = accB.z; dB[3] = accB.w;
    __syncthreads();

    for (int d = tid; d < D; d += 256) {
        float v = sp[0][d] + sp[1][d] + sp[2][d] + sp[3][d];
        atomicAdd(&s[b * D + d], v);
    }
}

// ---------------------------------------------------------------------------
// Pass 2: combined[b][n] = relevance + 0.3*diversity + 0.3*entropy
// ---------------------------------------------------------------------------
__global__ __launch_bounds__(256) void k_combined(const float* __restrict__ x,
                                                  const float* __restrict__ c,
                                                  const float* __restrict__ inv_norm,
                                                  const float* __restrict__ s,
                                                  float* __restrict__ combined) {
    __shared__ float sl[D];
    int blk  = blockIdx.x;
    int b    = blk / BLOCKS_PER_B;
    int rb   = (blk % BLOCKS_PER_B) * ROWS_PER_BLOCK;
    int tid  = threadIdx.x;
    int wave = tid >> 6;
    int lane = tid & 63;

    for (int d = tid; d < D; d += 256) sl[d] = s[b * D + d];
    __syncthreads();

    const float4* sv = (const float4*)sl;
    float4 sA = sv[lane];
    float4 sB = sv[64 + lane];

    const float4* xb = (const float4*)(x + (size_t)b * N * D);
    int row0 = rb + wave * ROWS_PER_WAVE;
    for (int r = 0; r < ROWS_PER_WAVE; ++r) {
        int row = row0 + r;
        const float4* xr = xb + (size_t)row * (D / 4);
        float4 a  = xr[lane];
        float4 bb = xr[64 + lane];

        float dot = a.x*sA.x + a.y*sA.y + a.z*sA.z + a.w*sA.w
                  + bb.x*sB.x + bb.y*sB.y + bb.z*sB.z + bb.w*sB.w;
        #pragma unroll
        for (int o = 32; o > 0; o >>= 1) dot += __shfl_xor(dot, o, 64);

        if (lane == 0) {
            float rs  = dot * inv_norm[b * N + row];
            float div = 1.0f - (rs - 1.0f) / (float)(N - 1);

            const float* cc = c + ((size_t)b * N + row) * C;
            float c0 = cc[0], c1 = cc[1];
            float rel = fmaxf(c0, c1);
            float m  = rel;
            float e0 = expf(c0 - m), e1 = expf(c1 - m);
            float Z  = e0 + e1;
            float p0 = e0 / Z, p1 = e1 / Z;
            float ent = -(p0 * logf(p0 + 1e-8f) + p1 * logf(p1 + 1e-8f));

            combined[b * N + row] = rel + DIV_W * div + UNC_W * ent;
        }
    }
}

// ---------------------------------------------------------------------------
// Pass 3 (fused): softmax over N + exact top-K via radix-select + 512-sort.
// One block of 512 threads per batch.
// ---------------------------------------------------------------------------
__global__ __launch_bounds__(512) void k_topk_sm(const float* __restrict__ combined,
                                                 float* __restrict__ out_idx,
                                                 float* __restrict__ out_w) {
    __shared__ uint32_t vals[N];        // 32 KB: ord-mapped values
    __shared__ float    ex[N];          // 32 KB: exp(x - m)
    __shared__ uint64_t cand[K];        // 4 KB: selected packed keys
    __shared__ uint32_t hist[256];
    __shared__ uint32_t tiew[256];      // tie bitmask, 8192 bits
    __shared__ uint32_t wred[8];
    __shared__ float    fred[8];
    __shared__ uint32_t sc_prefix, sc_remK, sc_cnt;

    const int b    = blockIdx.x;
    const int tid  = threadIdx.x;
    const int lane = tid & 63;
    const int wave = tid >> 6;
    const float* cb = combined + b * N;

    // ---- load + ord-map + running max --------------------------------------
    uint32_t umax = 0;
    const float4* cb4 = (const float4*)cb;
    for (int i4 = tid; i4 < N / 4; i4 += 512) {
        float4 f = cb4[i4];
        uint32_t u0 = ordmap(f.x), u1 = ordmap(f.y);
        uint32_t u2 = ordmap(f.z), u3 = ordmap(f.w);
        uint4 uu; uu.x = u0; uu.y = u1; uu.z = u2; uu.w = u3;
        ((uint4*)vals)[i4] = uu;
        umax = max(umax, max(max(u0, u1), max(u2, u3)));
    }
    #pragma unroll
    for (int o = 32; o > 0; o >>= 1) umax = max(umax, __shfl_xor(umax, o, 64));
    if (lane == 0) wred[wave] = umax;
    if (tid == 0) { sc_remK = K; sc_prefix = 0u; sc_cnt = 0u; }
    __syncthreads();
    uint32_t bmax = wred[0];
    #pragma unroll
    for (int q = 1; q < 8; ++q) bmax = max(bmax, wred[q]);
    const float m = ordunmap(bmax);

    // ---- softmax: sum of exp, then write weights ---------------------------
    float sum = 0.f;
    for (int i = tid; i < N; i += 512) {
        float e = expf(ordunmap(vals[i]) - m);
        ex[i] = e;
        sum += e;
    }
    #pragma unroll
    for (int o = 32; o > 0; o >>= 1) sum += __shfl_xor(sum, o, 64);
    if (lane == 0) fred[wave] = sum;
    __syncthreads();
    float Z = 0.f;
    #pragma unroll
    for (int q = 0; q < 8; ++q) Z += fred[q];
    const float invZ = 1.0f / Z;
    for (int i = tid; i < N; i += 512)
        out_w[b * N + i] = ex[i] * invZ;

    // ---- radix select: exact K-th largest u32 key --------------------------
    uint32_t prefix = 0, maskHi = 0;
    for (int p = 3; p >= 0; --p) {
        if (tid < 256) hist[tid] = 0u;
        __syncthreads();
        const int sh = 8 * p;
        for (int i = tid; i < N; i += 512) {
            uint32_t v = vals[i];
            if ((v & maskHi) == prefix)
                atomicAdd(&hist[(v >> sh) & 0xFFu], 1u);
        }
        __syncthreads();
        if (wave == 0) {
            uint32_t c[4], lsum = 0;
            #pragma unroll
            for (int q = 0; q < 4; ++q) { c[q] = hist[lane * 4 + q]; lsum += c[q]; }
            // suffix-inclusive sum across lanes (sum over lanes >= l)
            uint32_t ssum = lsum;
            #pragma unroll
            for (int off = 1; off < 64; off <<= 1) {
                uint32_t t2 = __shfl_down(ssum, off, 64);
                if (lane + off < 64) ssum += t2;
            }
            uint32_t cum = ssum - lsum;         // count strictly above this lane's bins
            const uint32_t remK = sc_remK;
            #pragma unroll
            for (int q = 3; q >= 0; --q) {
                if (cum < remK && cum + c[q] >= remK) {   // exactly one (lane,q) hits
                    sc_prefix = prefix | ((uint32_t)(lane * 4 + q) << sh);
                    sc_remK   = remK - cum;
                }
                cum += c[q];
            }
        }
        __syncthreads();
        prefix = sc_prefix;
        maskHi |= (0xFFu << sh);
    }
    const uint32_t T    = prefix;    // exact K-th largest value (ord space)
    const uint32_t remF = sc_remK;   // # of T-valued elements to take (lowest idx)

    // ---- compaction: strictly-greater + tie bitmask ------------------------
    if (tid < 256) tiew[tid] = 0u;
    __syncthreads();
    for (int i = tid; i < N; i += 512) {
        uint32_t v = vals[i];
        if (v > T) {
            uint32_t slot = atomicAdd(&sc_cnt, 1u);
            cand[slot] = ((uint64_t)v << 13) | (uint32_t)(8191 - i);
        } else if (v == T) {
            atomicOr(&tiew[i >> 5], 1u << (i & 31));
        }
    }
    __syncthreads();
    const uint32_t base = sc_cnt;    // == K - remF
    if (wave == 0) {
        const int w0 = lane * 4;
        uint32_t lsum = 0;
        #pragma unroll
        for (int q = 0; q < 4; ++q) lsum += __popc(tiew[w0 + q]);
        // exclusive ascending prefix across lanes
        uint32_t ssum = lsum;
        #pragma unroll
        for (int off = 1; off < 64; off <<= 1) {
            uint32_t t2 = __shfl_up(ssum, off, 64);
            if (lane >= off) ssum += t2;
        }
        uint32_t rank = ssum - lsum;
        for (int q = 0; q < 4; ++q) {
            uint32_t word = tiew[w0 + q];
            while (word) {
                int bpos = __builtin_ctz(word);
                if (rank < remF) {
                    uint32_t idx = (uint32_t)(w0 + q) * 32u + (uint32_t)bpos;
                    cand[base + rank] = ((uint64_t)T << 13) | (uint32_t)(8191 - idx);
                }
                rank++;
                word &= word - 1;
            }
        }
    }
    __syncthreads();

    // ---- bitonic sort of 512 unique keys, descending -----------------------
    uint64_t v = cand[tid];
    __syncthreads();
    for (int k = 2; k <= 512; k <<= 1) {
        for (int j = k >> 1; j > 0; j >>= 1) {
            const bool desc  = ((tid & k) == 0);
            const bool lower = ((tid & j) == 0);
            uint64_t pv;
            if (j >= 64) {
                cand[tid] = v;
                __syncthreads();
                pv = cand[tid ^ j];
                __syncthreads();
            } else {
                pv = __shfl_xor(v, j, 64);
            }
            const bool keepmax = (lower == desc);
            const bool take = keepmax ? (pv > v) : (pv < v);
            if (take) v = pv;
        }
    }
    out_idx[b * K + tid] = (float)(8191u - (uint32_t)(v & 0x1FFFu));
}

// ---------------------------------------------------------------------------
extern "C" void kernel_launch(void* const* d_in, const int* in_sizes, int n_in,
                              void* d_out, int out_size, void* d_ws, size_t ws_size,
                              hipStream_t stream) {
    const float* x = (const float*)d_in[0];
    const float* c = (const float*)d_in[1];

    float* ws       = (float*)d_ws;
    float* s        = ws;                  // B*D      = 4096 floats
    float* inv_norm = s + B * D;           // B*N      = 65536 floats
    float* combined = inv_norm + B * N;    // B*N      = 65536 floats

    float* out = (float*)d_out;            // [B*K indices][B*N weights]

    hipMemsetAsync(s, 0, B * D * sizeof(float), stream);

    k_norm_s  <<<B * BLOCKS_PER_B, 256, 0, stream>>>(x, inv_norm, s);
    k_combined<<<B * BLOCKS_PER_B, 256, 0, stream>>>(x, c, inv_norm, s, combined);
    k_topk_sm <<<B, 512, 0, stream>>>(combined, out, out + B * K);
}

// Round 3
// 78.427 us; speedup vs baseline: 2.4213x; 1.0402x over previous
//
#include <hip/hip_runtime.h>
#include <stdint.h>

#define B 8
#define N 8192
#define D 512
#define C 2
#define K 512
#define DIV_W 0.3f
#define UNC_W 0.3f

constexpr int ROWS_PER_WAVE  = 16;
constexpr int WAVES_PER_BLK  = 4;
constexpr int ROWS_PER_BLOCK = ROWS_PER_WAVE * WAVES_PER_BLK;  // 64
constexpr int BLOCKS_PER_B   = N / ROWS_PER_BLOCK;             // 128

// Order-preserving float<->u32 map (monotone: f1<f2 <=> ord(f1)<ord(f2))
__device__ __forceinline__ uint32_t ordmap(float f) {
    uint32_t u = __float_as_uint(f);
    return (u & 0x80000000u) ? ~u : (u | 0x80000000u);
}
__device__ __forceinline__ float ordunmap(uint32_t u) {
    return (u >> 31) ? __uint_as_float(u & 0x7FFFFFFFu) : __uint_as_float(~u);
}

// ---------------------------------------------------------------------------
// Pass 1: per-row inverse norm + per-block partial of s[b][d]
// ---------------------------------------------------------------------------
__global__ __launch_bounds__(256) void k_norm_s(const float* __restrict__ x,
                                                float* __restrict__ inv_norm,
                                                float* __restrict__ partials) {
    int blk  = blockIdx.x;
    int b    = blk / BLOCKS_PER_B;
    int rb   = (blk % BLOCKS_PER_B) * ROWS_PER_BLOCK;
    int tid  = threadIdx.x;
    int wave = tid >> 6;
    int lane = tid & 63;

    const float4* xb = (const float4*)(x + (size_t)b * N * D);

    float4 accA = {0.f, 0.f, 0.f, 0.f};
    float4 accB = {0.f, 0.f, 0.f, 0.f};

    int row0 = rb + wave * ROWS_PER_WAVE;
    for (int r = 0; r < ROWS_PER_WAVE; ++r) {
        int row = row0 + r;
        const float4* xr = xb + (size_t)row * (D / 4);
        float4 a  = xr[lane];
        float4 bb = xr[64 + lane];

        float ss = a.x*a.x + a.y*a.y + a.z*a.z + a.w*a.w
                 + bb.x*bb.x + bb.y*bb.y + bb.z*bb.z + bb.w*bb.w;
        #pragma unroll
        for (int o = 32; o > 0; o >>= 1) ss += __shfl_xor(ss, o, 64);

        float inv = 1.0f / fmaxf(sqrtf(ss), 1e-12f);
        if (lane == 0) inv_norm[b * N + row] = inv;

        accA.x += a.x * inv;  accA.y += a.y * inv;
        accA.z += a.z * inv;  accA.w += a.w * inv;
        accB.x += bb.x * inv; accB.y += bb.y * inv;
        accB.z += bb.z * inv; accB.w += bb.w * inv;
    }

    __shared__ float sp[WAVES_PER_BLK][D];
    float* dA = &sp[wave][lane * 4];
    dA[0] = accA.x; dA[1] = accA.y; dA[2] = accA.z; dA[3] = accA.w;
    float* dB = &sp[wave][256 + lane * 4];
    dB[0] = accB.x; dB[1] = accB.y; dB[2] = accB.z; dB[3] = accB.w;
    __syncthreads();

    float* dst = partials + (size_t)blk * D;
    for (int d = tid; d < D; d += 256)
        dst[d] = sp[0][d] + sp[1][d] + sp[2][d] + sp[3][d];
}

// ---------------------------------------------------------------------------
// Pass 1b: s[b][d] = sum over the 128 block partials (L2-resident, ~2 us)
// ---------------------------------------------------------------------------
__global__ __launch_bounds__(512) void k_reduce_s(const float* __restrict__ partials,
                                                  float* __restrict__ s) {
    int b = blockIdx.x;
    int d = threadIdx.x;          // 512 == D
    const float* p = partials + (size_t)b * BLOCKS_PER_B * D + d;
    float acc = 0.f;
    #pragma unroll 8
    for (int j = 0; j < BLOCKS_PER_B; ++j) acc += p[(size_t)j * D];
    s[b * D + d] = acc;
}

// ---------------------------------------------------------------------------
// Pass 2: combined[b][n] = relevance + 0.3*diversity + 0.3*entropy
// ---------------------------------------------------------------------------
__global__ __launch_bounds__(256) void k_combined(const float* __restrict__ x,
                                                  const float* __restrict__ c,
                                                  const float* __restrict__ inv_norm,
                                                  const float* __restrict__ s,
                                                  float* __restrict__ combined) {
    __shared__ float sl[D];
    int blk  = blockIdx.x;
    int b    = blk / BLOCKS_PER_B;
    int rb   = (blk % BLOCKS_PER_B) * ROWS_PER_BLOCK;
    int tid  = threadIdx.x;
    int wave = tid >> 6;
    int lane = tid & 63;

    for (int d = tid; d < D; d += 256) sl[d] = s[b * D + d];
    __syncthreads();

    const float4* sv = (const float4*)sl;
    float4 sA = sv[lane];
    float4 sB = sv[64 + lane];

    const float4* xb = (const float4*)(x + (size_t)b * N * D);
    int row0 = rb + wave * ROWS_PER_WAVE;
    for (int r = 0; r < ROWS_PER_WAVE; ++r) {
        int row = row0 + r;
        const float4* xr = xb + (size_t)row * (D / 4);
        float4 a  = xr[lane];
        float4 bb = xr[64 + lane];

        float dot = a.x*sA.x + a.y*sA.y + a.z*sA.z + a.w*sA.w
                  + bb.x*sB.x + bb.y*sB.y + bb.z*sB.z + bb.w*sB.w;
        #pragma unroll
        for (int o = 32; o > 0; o >>= 1) dot += __shfl_xor(dot, o, 64);

        if (lane == 0) {
            float rs  = dot * inv_norm[b * N + row];
            float div = 1.0f - (rs - 1.0f) / (float)(N - 1);

            const float* cc = c + ((size_t)b * N + row) * C;
            float c0 = cc[0], c1 = cc[1];
            float rel = fmaxf(c0, c1);
            float e0 = expf(c0 - rel), e1 = expf(c1 - rel);
            float Z  = e0 + e1;
            float p0 = e0 / Z, p1 = e1 / Z;
            float ent = -(p0 * logf(p0 + 1e-8f) + p1 * logf(p1 + 1e-8f));

            combined[b * N + row] = rel + DIV_W * div + UNC_W * ent;
        }
    }
}

// ---------------------------------------------------------------------------
// Pass 3 (fused): softmax over N + exact top-K (radix select + 512-sort).
// One block of 1024 threads per batch; the 8 values/thread live in VGPRs.
// ---------------------------------------------------------------------------
__global__ __launch_bounds__(1024) void k_topk_sm(const float* __restrict__ combined,
                                                  float* __restrict__ out_idx,
                                                  float* __restrict__ out_w) {
    __shared__ uint64_t cand[K];        // 4 KB
    __shared__ uint32_t hist[256];
    __shared__ uint32_t tiew[256];      // tie bitmask, 8192 bits
    __shared__ uint32_t wred[16];
    __shared__ float    fred[16];
    __shared__ uint32_t sc_prefix, sc_remK, sc_cnt;

    const int b    = blockIdx.x;
    const int tid  = threadIdx.x;
    const int lane = tid & 63;
    const int wave = tid >> 6;

    // element index of register slot q: q<4 -> 4*tid+q ; q>=4 -> 4096+4*tid+(q-4)
    const float4* cb4 = (const float4*)(combined + b * N);
    float4 f0 = cb4[tid];
    float4 f1 = cb4[1024 + tid];

    uint32_t v[8];
    v[0] = ordmap(f0.x); v[1] = ordmap(f0.y); v[2] = ordmap(f0.z); v[3] = ordmap(f0.w);
    v[4] = ordmap(f1.x); v[5] = ordmap(f1.y); v[6] = ordmap(f1.z); v[7] = ordmap(f1.w);

    uint32_t umax = 0;
    #pragma unroll
    for (int q = 0; q < 8; ++q) umax = max(umax, v[q]);
    #pragma unroll
    for (int o = 32; o > 0; o >>= 1) umax = max(umax, __shfl_xor(umax, o, 64));
    if (lane == 0) wred[wave] = umax;
    if (tid == 0) { sc_remK = K; sc_prefix = 0u; sc_cnt = 0u; }
    __syncthreads();
    uint32_t bmax = wred[0];
    #pragma unroll
    for (int q = 1; q < 16; ++q) bmax = max(bmax, wred[q]);
    const float m = ordunmap(bmax);

    // ---- softmax ----------------------------------------------------------
    float e[8];
    float sum = 0.f;
    #pragma unroll
    for (int q = 0; q < 8; ++q) { e[q] = expf(ordunmap(v[q]) - m); sum += e[q]; }
    #pragma unroll
    for (int o = 32; o > 0; o >>= 1) sum += __shfl_xor(sum, o, 64);
    if (lane == 0) fred[wave] = sum;
    __syncthreads();
    float Z = 0.f;
    #pragma unroll
    for (int q = 0; q < 16; ++q) Z += fred[q];
    const float invZ = 1.0f / Z;
    float4* ow = (float4*)(out_w + b * N);
    float4 w0 = {e[0]*invZ, e[1]*invZ, e[2]*invZ, e[3]*invZ};
    float4 w1 = {e[4]*invZ, e[5]*invZ, e[6]*invZ, e[7]*invZ};
    ow[tid]        = w0;
    ow[1024 + tid] = w1;

    // ---- radix select: exact K-th largest u32 key -------------------------
    uint32_t prefix = 0, maskHi = 0;
    for (int p = 3; p >= 0; --p) {
        if (tid < 256) hist[tid] = 0u;
        __syncthreads();
        const int sh = 8 * p;
        #pragma unroll
        for (int q = 0; q < 8; ++q) {
            if ((v[q] & maskHi) == prefix)
                atomicAdd(&hist[(v[q] >> sh) & 0xFFu], 1u);
        }
        __syncthreads();
        if (wave == 0) {
            uint32_t cc[4], lsum = 0;
            #pragma unroll
            for (int q = 0; q < 4; ++q) { cc[q] = hist[lane * 4 + q]; lsum += cc[q]; }
            // suffix-inclusive sum across lanes (sum over lanes >= l)
            uint32_t ssum = lsum;
            #pragma unroll
            for (int off = 1; off < 64; off <<= 1) {
                uint32_t t2 = __shfl_down(ssum, off, 64);
                if (lane + off < 64) ssum += t2;
            }
            uint32_t cum = ssum - lsum;          // count strictly above this lane's bins
            const uint32_t remK = sc_remK;
            #pragma unroll
            for (int q = 3; q >= 0; --q) {
                if (cum < remK && cum + cc[q] >= remK) {  // exactly one (lane,q) hits
                    sc_prefix = prefix | ((uint32_t)(lane * 4 + q) << sh);
                    sc_remK   = remK - cum;
                }
                cum += cc[q];
            }
        }
        __syncthreads();
        prefix = sc_prefix;
        maskHi |= (0xFFu << sh);
    }
    const uint32_t T    = prefix;    // exact K-th largest value (ord space)
    const uint32_t remF = sc_remK;   // # of T-valued elements to take (lowest idx)

    // ---- compaction: strictly-greater + tie bitmask -----------------------
    if (tid < 256) tiew[tid] = 0u;
    __syncthreads();
    #pragma unroll
    for (int q = 0; q < 8; ++q) {
        uint32_t idx = (q < 4) ? (uint32_t)(4 * tid + q)
                               : (uint32_t)(4096 + 4 * tid + (q - 4));
        if (v[q] > T) {
            uint32_t slot = atomicAdd(&sc_cnt, 1u);
            cand[slot] = ((uint64_t)v[q] << 13) | (uint32_t)(8191 - idx);
        } else if (v[q] == T) {
            atomicOr(&tiew[idx >> 5], 1u << (idx & 31));
        }
    }
    __syncthreads();
    const uint32_t base = sc_cnt;    // == K - remF
    if (wave == 0) {
        const int w0i = lane * 4;
        uint32_t lsum = 0;
        #pragma unroll
        for (int q = 0; q < 4; ++q) lsum += __popc(tiew[w0i + q]);
        uint32_t ssum = lsum;
        #pragma unroll
        for (int off = 1; off < 64; off <<= 1) {
            uint32_t t2 = __shfl_up(ssum, off, 64);
            if (lane >= off) ssum += t2;
        }
        uint32_t rank = ssum - lsum;             // exclusive prefix (ascending idx)
        for (int q = 0; q < 4; ++q) {
            uint32_t word = tiew[w0i + q];
            while (word) {
                int bpos = __builtin_ctz(word);
                if (rank < remF) {
                    uint32_t idx = (uint32_t)(w0i + q) * 32u + (uint32_t)bpos;
                    cand[base + rank] = ((uint64_t)T << 13) | (uint32_t)(8191 - idx);
                }
                rank++;
                word &= word - 1;
            }
        }
    }
    __syncthreads();

    // ---- bitonic sort of 512 unique keys, descending ----------------------
    uint64_t sv = (tid < K) ? cand[tid] : 0ULL;
    __syncthreads();
    for (int k = 2; k <= K; k <<= 1) {
        for (int j = k >> 1; j > 0; j >>= 1) {
            const bool desc  = ((tid & k) == 0);
            const bool lower = ((tid & j) == 0);
            uint64_t pv;
            if (j >= 64) {
                if (tid < K) cand[tid] = sv;
                __syncthreads();
                pv = (tid < K) ? cand[tid ^ j] : 0ULL;
                __syncthreads();
            } else {
                pv = __shfl_xor(sv, j, 64);
            }
            const bool keepmax = (lower == desc);
            if (tid < K && (keepmax ? (pv > sv) : (pv < sv))) sv = pv;
        }
    }
    if (tid < K)
        out_idx[b * K + tid] = (float)(8191u - (uint32_t)(sv & 0x1FFFu));
}

// ---------------------------------------------------------------------------
extern "C" void kernel_launch(void* const* d_in, const int* in_sizes, int n_in,
                              void* d_out, int out_size, void* d_ws, size_t ws_size,
                              hipStream_t stream) {
    const float* x = (const float*)d_in[0];
    const float* c = (const float*)d_in[1];

    float* ws       = (float*)d_ws;
    float* partials = ws;                              // B*128*D = 524288 floats (2 MB)
    float* s        = partials + B * BLOCKS_PER_B * D; // B*D     = 4096 floats
    float* inv_norm = s + B * D;                       // B*N     = 65536 floats
    float* combined = inv_norm + B * N;                // B*N     = 65536 floats

    float* out = (float*)d_out;                        // [B*K indices][B*N weights]

    k_norm_s  <<<B * BLOCKS_PER_B, 256, 0, stream>>>(x, inv_norm, partials);
    k_reduce_s<<<B, 512, 0, stream>>>(partials, s);
    k_combined<<<B * BLOCKS_PER_B, 256, 0, stream>>>(x, c, inv_norm, s, combined);
    k_topk_sm <<<B, 1024, 0, stream>>>(combined, out, out + B * K);
}